// Round 7
// baseline (74.621 us; speedup 1.0000x reference)
//
#include <hip/hip_runtime.h>
#include <hip/hip_bf16.h>
#include <hip/hip_fp16.h>

typedef __attribute__((ext_vector_type(8))) short short8;
typedef __attribute__((ext_vector_type(8))) _Float16 half8;
typedef __attribute__((ext_vector_type(4))) float f32x4;

#define MAXNBR 128
#define ALPHA 0.2f

static __device__ __forceinline__ unsigned short f2h(float f) {
    return __half_as_ushort(__float2half(f));
}
static __device__ __forceinline__ float h2f(unsigned short u) {
    return __half2float(__ushort_as_half(u));
}

// ---------- K0: cvt x -> f16, W1 -> W1t f16 ----------
__global__ __launch_bounds__(256) void cvt(const float* __restrict__ x,
                                           unsigned short* __restrict__ xh,
                                           const float* __restrict__ W1,
                                           unsigned short* __restrict__ W1t) {
    int b = blockIdx.x, t = threadIdx.x;
    if (b < 1024) {                       // x: 8 elems/thread
        size_t base = (size_t)b * 2048 + t * 8;
        float4 v0 = *(const float4*)&x[base];
        float4 v1 = *(const float4*)&x[base + 4];
        short8 o;
        o[0] = f2h(v0.x); o[1] = f2h(v0.y); o[2] = f2h(v0.z); o[3] = f2h(v0.w);
        o[4] = f2h(v1.x); o[5] = f2h(v1.y); o[6] = f2h(v1.z); o[7] = f2h(v1.w);
        *(short8*)&xh[base] = o;
    } else {                              // W1t transpose: 1 elem/thread
        int idx = (b - 1024) * 256 + t;   // out index c*512+k
        int c = idx >> 9, k = idx & 511;
        W1t[idx] = f2h(W1[(size_t)k * 1024 + c]);
    }
}

// ---------- K1: fused GEMM (512 blocks) + adjacency scan (1024 blocks) ----------
__global__ __launch_bounds__(256) void gemm_scan(const unsigned short* __restrict__ A,
                                                 const unsigned short* __restrict__ Bt,
                                                 unsigned short* __restrict__ C,
                                                 const float* __restrict__ adj,
                                                 int* __restrict__ nbr_idx,
                                                 int* __restrict__ nbr_cnt) {
    __shared__ unsigned short Asm[128 * 64];   // 16 KB
    __shared__ unsigned short Bsm[64 * 64];    //  8 KB
    int b = blockIdx.x;
    int tid = threadIdx.x;
    if (b < 512) {
        int lane = tid & 63;
        int w = tid >> 6;
        int wr = w >> 1, wc = w & 1;           // waves 2x2; wave tile 64x32
        int rowBase = (b & 31) * 128, colBase = (b >> 5) * 64;
        int lr = lane >> 3;
        int lc = (lane & 7) * 8;
        f32x4 acc[4][2] = {};
        for (int k0 = 0; k0 < 512; k0 += 64) {
            #pragma unroll
            for (int i = 0; i < 4; ++i) {
                int rA = i * 32 + w * 8;
                __builtin_amdgcn_global_load_lds(
                    (const __attribute__((address_space(1))) void*)&A[(size_t)(rowBase + rA + lr) * 512 + k0 + lc],
                    (__attribute__((address_space(3))) void*)&Asm[rA * 64],
                    16, 0, 0);
            }
            #pragma unroll
            for (int i = 0; i < 2; ++i) {
                int rB = i * 32 + w * 8;
                __builtin_amdgcn_global_load_lds(
                    (const __attribute__((address_space(1))) void*)&Bt[(size_t)(colBase + rB + lr) * 512 + k0 + lc],
                    (__attribute__((address_space(3))) void*)&Bsm[rB * 64],
                    16, 0, 0);
            }
            __syncthreads();
            #pragma unroll
            for (int kk = 0; kk < 64; kk += 32) {
                half8 af[4], bfv[2];
                int kf = kk + (lane >> 4) * 8;
                #pragma unroll
                for (int m = 0; m < 4; ++m)
                    af[m] = *(const half8*)&Asm[(wr * 64 + m * 16 + (lane & 15)) * 64 + kf];
                #pragma unroll
                for (int n = 0; n < 2; ++n)
                    bfv[n] = *(const half8*)&Bsm[(wc * 32 + n * 16 + (lane & 15)) * 64 + kf];
                #pragma unroll
                for (int m = 0; m < 4; ++m)
                    #pragma unroll
                    for (int n = 0; n < 2; ++n)
                        acc[m][n] = __builtin_amdgcn_mfma_f32_16x16x32_f16(af[m], bfv[n], acc[m][n], 0, 0, 0);
            }
            __syncthreads();
        }
        int crow0 = rowBase + wr * 64, ccol0 = colBase + wc * 32;
        #pragma unroll
        for (int m = 0; m < 4; ++m)
            #pragma unroll
            for (int n = 0; n < 2; ++n) {
                int col = ccol0 + n * 16 + (lane & 15);
                int row0 = crow0 + m * 16 + (lane >> 4) * 4;
                #pragma unroll
                for (int r = 0; r < 4; ++r)
                    C[(size_t)(row0 + r) * 1024 + col] = f2h(acc[m][n][r]);
            }
    } else {
        // ----- adjacency scan: 4 rows/block, one wave each -----
        int row = (b - 512) * 4 + (tid >> 6);
        int lane = tid & 63;
        const float* arow = adj + (size_t)row * 4096;
        int cnt = 0;
        for (int base = 0; base < 4096; base += 256) {
            float4 v = *(const float4*)&arow[base + lane * 4];
            #pragma unroll
            for (int s = 0; s < 4; ++s) {
                float xv = ((const float*)&v)[s];
                unsigned long long m = __ballot(xv > 0.f);
                if (xv > 0.f) {
                    int pos = cnt + (int)__popcll(m & ((1ull << lane) - 1ull));
                    if (pos < MAXNBR) nbr_idx[row * MAXNBR + pos] = base + lane * 4 + s;
                }
                cnt += (int)__popcll(m);
            }
        }
        if (lane == 0) nbr_cnt[row] = cnt < MAXNBR ? cnt : MAXNBR;
    }
}

// ---------- K2: f_src1/f_dst1 [8][4096] from f16 h1 ----------
__global__ __launch_bounds__(256) void attn_coef1(const unsigned short* __restrict__ h1h,
                                                  const float* __restrict__ a_src,
                                                  const float* __restrict__ a_dst,
                                                  float* __restrict__ f_src,
                                                  float* __restrict__ f_dst) {
    int n = blockIdx.x, t = threadIdx.x;
    ushort4 v = *(const ushort4*)&h1h[(size_t)n * 1024 + t * 4];
    int head = t >> 5;
    int o0 = (t * 4) & 127;
    float hv0 = h2f(v.x), hv1 = h2f(v.y), hv2 = h2f(v.z), hv3 = h2f(v.w);
    float ps = hv0 * a_src[head * 128 + o0] + hv1 * a_src[head * 128 + o0 + 1]
             + hv2 * a_src[head * 128 + o0 + 2] + hv3 * a_src[head * 128 + o0 + 3];
    float pd = hv0 * a_dst[head * 128 + o0] + hv1 * a_dst[head * 128 + o0 + 1]
             + hv2 * a_dst[head * 128 + o0 + 2] + hv3 * a_dst[head * 128 + o0 + 3];
    #pragma unroll
    for (int off = 1; off < 32; off <<= 1) {
        ps += __shfl_xor(ps, off);
        pd += __shfl_xor(pd, off);
    }
    if ((t & 31) == 0) {
        f_src[head * 4096 + n] = ps;
        f_dst[head * 4096 + n] = pd;
    }
}

// ---------- K3: aggregate4 — 1 node/block, 4 waves = {feat-half x nbr-parity} ----------
// Lane loads 16B (8 f16 feats): 1 KB per wave-instr; parity split gives 2
// independent row streams. Halves VMEM instr count vs aggregate3.
__global__ __launch_bounds__(256, 8) void aggregate4(const unsigned short* __restrict__ h1h,
                                                     const int* __restrict__ nbr_idx,
                                                     const int* __restrict__ nbr_cnt,
                                                     const float* __restrict__ f_src,
                                                     const float* __restrict__ f_dst,
                                                     unsigned short* __restrict__ h1act) {
    __shared__ int nbr[MAXNBR];
    __shared__ float attw[8][MAXNBR];
    __shared__ float part[2][64][8];
    int i = blockIdx.x;
    int t = threadIdx.x;
    int lane = t & 63;
    int w = t >> 6;
    int cnt = nbr_cnt[i];
    if (t < MAXNBR) nbr[t] = (t < cnt) ? nbr_idx[i * MAXNBR + t] : 0;
    __syncthreads();
    // ---- one-pass softmax: thread t -> head t>>5, slots (t&31)+32p ----
    {
        int h = t >> 5, sl = t & 31;
        float fsh = f_src[h * 4096 + i];
        float e[4];
        #pragma unroll
        for (int p = 0; p < 4; ++p) {
            int j = sl + p * 32;
            if (j < cnt) {
                float xv = fsh + f_dst[h * 4096 + nbr[j]];
                e[p] = xv > 0.f ? xv : ALPHA * xv;
            } else e[p] = -INFINITY;
        }
        float m = fmaxf(fmaxf(e[0], e[1]), fmaxf(e[2], e[3]));
        #pragma unroll
        for (int off = 1; off < 32; off <<= 1) m = fmaxf(m, __shfl_xor(m, off));
        float wq[4], s = 0.f;
        #pragma unroll
        for (int p = 0; p < 4; ++p) {
            wq[p] = (e[p] == -INFINITY) ? 0.f : __expf(e[p] - m);
            s += wq[p];
        }
        #pragma unroll
        for (int off = 1; off < 32; off <<= 1) s += __shfl_xor(s, off);
        float inv = 1.f / s;
        #pragma unroll
        for (int p = 0; p < 4; ++p) attw[h][sl + p * 32] = wq[p] * inv;
    }
    __syncthreads();
    // ---- gather: wave w -> parity w&1, feature-half w>>1; lane owns 8 feats ----
    int par = w & 1, half = w >> 1;
    int head = half * 4 + (lane >> 4);
    const unsigned short* src = h1h + half * 512 + lane * 8;
    float acc[8] = {0.f, 0.f, 0.f, 0.f, 0.f, 0.f, 0.f, 0.f};
    int cntPad = (cnt + 3) & ~3;
    for (int j = par; j < cntPad; j += 4) {
        int nb1 = nbr[j], nb2 = nbr[j + 2];
        float w1 = attw[head][j], w2 = attw[head][j + 2];
        half8 v1 = *(const half8*)&src[(size_t)nb1 << 10];
        half8 v2 = *(const half8*)&src[(size_t)nb2 << 10];
        #pragma unroll
        for (int k = 0; k < 8; ++k)
            acc[k] += w1 * (float)v1[k] + w2 * (float)v2[k];
    }
    if (par == 1) {
        #pragma unroll
        for (int k = 0; k < 8; ++k) part[half][lane][k] = acc[k];
    }
    __syncthreads();
    if (par == 0) {
        short8 o;
        #pragma unroll
        for (int k = 0; k < 8; ++k) {
            float a = acc[k] + part[half][lane][k];
            a = a > 0.f ? a : (__expf(a) - 1.f);
            o[k] = f2h(a);
        }
        *(short8*)&h1act[(size_t)i * 1024 + half * 512 + lane * 8] = o;
    }
}

// ---------- K4: layer-2 as MFMA GEMM [4096x1024]@[1024x16] + fused f2 coefs ----------
__global__ __launch_bounds__(256) void layer2_mfma(const unsigned short* __restrict__ h1act,
                                                   const float* __restrict__ W2,
                                                   const float* __restrict__ a_src2,
                                                   const float* __restrict__ a_dst2,
                                                   float* __restrict__ h2,
                                                   float* __restrict__ f_src2,
                                                   float* __restrict__ f_dst2) {
    __shared__ unsigned short Asm2[64 * 64];       // 8 KB: 64 rows x 64 k
    __shared__ unsigned short W2t[16 * 1032];      // 33 KB: [col][k], padded +8
    int t = threadIdx.x, lane = t & 63, w = t >> 6;
    int rowBase = blockIdx.x * 64;
    for (int idx = t; idx < 16384; idx += 256) {
        int k = idx >> 4, o = idx & 15;
        W2t[o * 1032 + k] = f2h(W2[idx]);
    }
    f32x4 acc = {};
    __syncthreads();
    for (int k0 = 0; k0 < 1024; k0 += 64) {
        #pragma unroll
        for (int r = 0; r < 2; ++r) {
            int rA = r * 32 + w * 8;
            __builtin_amdgcn_global_load_lds(
                (const __attribute__((address_space(1))) void*)&h1act[(size_t)(rowBase + rA + (lane >> 3)) * 1024 + k0 + (lane & 7) * 8],
                (__attribute__((address_space(3))) void*)&Asm2[rA * 64],
                16, 0, 0);
        }
        __syncthreads();
        #pragma unroll
        for (int kk = 0; kk < 64; kk += 32) {
            half8 af = *(const half8*)&Asm2[(w * 16 + (lane & 15)) * 64 + kk + (lane >> 4) * 8];
            half8 bf = *(const half8*)&W2t[(lane & 15) * 1032 + k0 + kk + (lane >> 4) * 8];
            acc = __builtin_amdgcn_mfma_f32_16x16x32_f16(af, bf, acc, 0, 0, 0);
        }
        __syncthreads();
    }
    int col = lane & 15;
    int g = lane >> 4;
    #pragma unroll
    for (int r = 0; r < 4; ++r) {
        int row = rowBase + w * 16 + g * 4 + r;
        float v = acc[r];
        h2[row * 16 + col] = v;
        float ps = v * a_src2[col];
        float pd = v * a_dst2[col];
        #pragma unroll
        for (int off = 1; off < 16; off <<= 1) {
            ps += __shfl_xor(ps, off);
            pd += __shfl_xor(pd, off);
        }
        if (col == 0) { f_src2[row] = ps; f_dst2[row] = pd; }
    }
}

// ---------- K5: layer-2 aggregation + elu + log_softmax ----------
__global__ __launch_bounds__(64) void final_layer(const float* __restrict__ h2,
                                                  const int* __restrict__ nbr_idx,
                                                  const int* __restrict__ nbr_cnt,
                                                  const float* __restrict__ f_src2,
                                                  const float* __restrict__ f_dst2,
                                                  float* __restrict__ out) {
    __shared__ float attn[MAXNBR];
    __shared__ int nbr[MAXNBR];
    int i = blockIdx.x;
    int l = threadIdx.x;
    int cnt = nbr_cnt[i];
    float fsi = f_src2[i];
    for (int j = l; j < MAXNBR; j += 64) {
        float e = -INFINITY;
        if (j < cnt) {
            int jj = nbr_idx[i * MAXNBR + j];
            nbr[j] = jj;
            float xv = fsi + f_dst2[jj];
            e = xv > 0.f ? xv : ALPHA * xv;
        }
        attn[j] = e;
    }
    __syncthreads();
    float m = fmaxf(attn[l], attn[l + 64]);
    #pragma unroll
    for (int off = 1; off < 64; off <<= 1) m = fmaxf(m, __shfl_xor(m, off));
    float s = 0.f;
    {
        float e0 = attn[l], e1 = attn[l + 64];
        if (e0 != -INFINITY) s += __expf(e0 - m);
        if (e1 != -INFINITY) s += __expf(e1 - m);
    }
    #pragma unroll
    for (int off = 1; off < 64; off <<= 1) s += __shfl_xor(s, off);
    for (int j = l; j < MAXNBR; j += 64) {
        float e = attn[j];
        attn[j] = (e == -INFINITY) ? 0.f : __expf(e - m) / s;
    }
    __syncthreads();
    if (l < 16) {
        float acc = 0.f;
        for (int j = 0; j < cnt; ++j)
            acc += attn[j] * h2[nbr[j] * 16 + l];
        float v = acc > 0.f ? acc : expm1f(acc);
        float mx = v;
        #pragma unroll
        for (int off = 1; off < 16; off <<= 1) mx = fmaxf(mx, __shfl_xor(mx, off));
        float se = __expf(v - mx);
        #pragma unroll
        for (int off = 1; off < 16; off <<= 1) se += __shfl_xor(se, off);
        out[i * 16 + l] = v - mx - logf(se);
    }
}

extern "C" void kernel_launch(void* const* d_in, const int* in_sizes, int n_in,
                              void* d_out, int out_size, void* d_ws, size_t ws_size,
                              hipStream_t stream) {
    const float* x      = (const float*)d_in[0];
    const float* adj    = (const float*)d_in[1];
    const float* W1     = (const float*)d_in[2];
    const float* a_src1 = (const float*)d_in[3];
    const float* a_dst1 = (const float*)d_in[4];
    const float* W2     = (const float*)d_in[5];
    const float* a_src2 = (const float*)d_in[6];
    const float* a_dst2 = (const float*)d_in[7];
    float* out = (float*)d_out;

    char* ws = (char*)d_ws;
    unsigned short* xh    = (unsigned short*)ws;                      // 4 MB
    unsigned short* w1t   = (unsigned short*)(ws + (4u << 20));       // 1 MB
    unsigned short* h1h   = (unsigned short*)(ws + (6u << 20));       // 8 MB
    unsigned short* h1act = (unsigned short*)(ws + (26u << 20));      // 8 MB
    float* fsrc1 = (float*)(ws + (14u << 20));                        // 128 KB
    float* fdst1 = (float*)(ws + (14u << 20) + (128u << 10));         // 128 KB
    float* h2    = (float*)(ws + (15u << 20));                        // 256 KB
    float* fsrc2 = (float*)(ws + (15u << 20) + (256u << 10));         // 16 KB
    float* fdst2 = (float*)(ws + (15u << 20) + (272u << 10));         // 16 KB
    int* nbr_idx = (int*)(ws + (16u << 20));                          // 2 MB
    int* nbr_cnt = (int*)(ws + (18u << 20));                          // 16 KB

    cvt<<<3072, 256, 0, stream>>>(x, xh, W1, w1t);
    gemm_scan<<<1536, 256, 0, stream>>>(xh, w1t, h1h, adj, nbr_idx, nbr_cnt);
    attn_coef1<<<4096, 256, 0, stream>>>(h1h, a_src1, a_dst1, fsrc1, fdst1);
    aggregate4<<<4096, 256, 0, stream>>>(h1h, nbr_idx, nbr_cnt, fsrc1, fdst1, h1act);
    layer2_mfma<<<64, 256, 0, stream>>>(h1act, W2, a_src2, a_dst2, h2, fsrc2, fdst2);
    final_layer<<<4096, 64, 0, stream>>>(h2, nbr_idx, nbr_cnt, fsrc2, fdst2, out);
}

// Round 8
// 72.949 us; speedup vs baseline: 1.0229x; 1.0229x over previous
//
#include <hip/hip_runtime.h>
#include <hip/hip_bf16.h>
#include <hip/hip_fp16.h>

typedef __attribute__((ext_vector_type(8))) short short8;
typedef __attribute__((ext_vector_type(8))) _Float16 half8;
typedef __attribute__((ext_vector_type(2))) _Float16 h2v;
typedef __attribute__((ext_vector_type(4))) float f32x4;

#define MAXNBR 128
#define ALPHA 0.2f

static __device__ __forceinline__ unsigned short f2h(float f) {
    return __half_as_ushort(__float2half(f));
}
static __device__ __forceinline__ float h2f(unsigned short u) {
    return __half2float(__ushort_as_half(u));
}

// ---------- K0: cvt x -> f16, W1 -> W1t f16 ----------
__global__ __launch_bounds__(256) void cvt(const float* __restrict__ x,
                                           unsigned short* __restrict__ xh,
                                           const float* __restrict__ W1,
                                           unsigned short* __restrict__ W1t) {
    int b = blockIdx.x, t = threadIdx.x;
    if (b < 1024) {                       // x: 8 elems/thread
        size_t base = (size_t)b * 2048 + t * 8;
        float4 v0 = *(const float4*)&x[base];
        float4 v1 = *(const float4*)&x[base + 4];
        short8 o;
        o[0] = f2h(v0.x); o[1] = f2h(v0.y); o[2] = f2h(v0.z); o[3] = f2h(v0.w);
        o[4] = f2h(v1.x); o[5] = f2h(v1.y); o[6] = f2h(v1.z); o[7] = f2h(v1.w);
        *(short8*)&xh[base] = o;
    } else {                              // W1t transpose: 1 elem/thread
        int idx = (b - 1024) * 256 + t;   // out index c*512+k
        int c = idx >> 9, k = idx & 511;
        W1t[idx] = f2h(W1[(size_t)k * 1024 + c]);
    }
}

// ---------- K1: fused GEMM (512 blocks) + adjacency scan (1024 blocks) ----------
__global__ __launch_bounds__(256) void gemm_scan(const unsigned short* __restrict__ A,
                                                 const unsigned short* __restrict__ Bt,
                                                 unsigned short* __restrict__ C,
                                                 const float* __restrict__ adj,
                                                 int* __restrict__ nbr_idx,
                                                 int* __restrict__ nbr_cnt) {
    __shared__ unsigned short Asm[128 * 64];   // 16 KB
    __shared__ unsigned short Bsm[64 * 64];    //  8 KB
    int b = blockIdx.x;
    int tid = threadIdx.x;
    if (b < 512) {
        int lane = tid & 63;
        int w = tid >> 6;
        int wr = w >> 1, wc = w & 1;           // waves 2x2; wave tile 64x32
        int rowBase = (b & 31) * 128, colBase = (b >> 5) * 64;
        int lr = lane >> 3;
        int lc = (lane & 7) * 8;
        f32x4 acc[4][2] = {};
        for (int k0 = 0; k0 < 512; k0 += 64) {
            #pragma unroll
            for (int i = 0; i < 4; ++i) {
                int rA = i * 32 + w * 8;
                __builtin_amdgcn_global_load_lds(
                    (const __attribute__((address_space(1))) void*)&A[(size_t)(rowBase + rA + lr) * 512 + k0 + lc],
                    (__attribute__((address_space(3))) void*)&Asm[rA * 64],
                    16, 0, 0);
            }
            #pragma unroll
            for (int i = 0; i < 2; ++i) {
                int rB = i * 32 + w * 8;
                __builtin_amdgcn_global_load_lds(
                    (const __attribute__((address_space(1))) void*)&Bt[(size_t)(colBase + rB + lr) * 512 + k0 + lc],
                    (__attribute__((address_space(3))) void*)&Bsm[rB * 64],
                    16, 0, 0);
            }
            __syncthreads();
            #pragma unroll
            for (int kk = 0; kk < 64; kk += 32) {
                half8 af[4], bfv[2];
                int kf = kk + (lane >> 4) * 8;
                #pragma unroll
                for (int m = 0; m < 4; ++m)
                    af[m] = *(const half8*)&Asm[(wr * 64 + m * 16 + (lane & 15)) * 64 + kf];
                #pragma unroll
                for (int n = 0; n < 2; ++n)
                    bfv[n] = *(const half8*)&Bsm[(wc * 32 + n * 16 + (lane & 15)) * 64 + kf];
                #pragma unroll
                for (int m = 0; m < 4; ++m)
                    #pragma unroll
                    for (int n = 0; n < 2; ++n)
                        acc[m][n] = __builtin_amdgcn_mfma_f32_16x16x32_f16(af[m], bfv[n], acc[m][n], 0, 0, 0);
            }
            __syncthreads();
        }
        int crow0 = rowBase + wr * 64, ccol0 = colBase + wc * 32;
        #pragma unroll
        for (int m = 0; m < 4; ++m)
            #pragma unroll
            for (int n = 0; n < 2; ++n) {
                int col = ccol0 + n * 16 + (lane & 15);
                int row0 = crow0 + m * 16 + (lane >> 4) * 4;
                #pragma unroll
                for (int r = 0; r < 4; ++r)
                    C[(size_t)(row0 + r) * 1024 + col] = f2h(acc[m][n][r]);
            }
    } else {
        // ----- adjacency scan: 4 rows/block, one wave each -----
        int row = (b - 512) * 4 + (tid >> 6);
        int lane = tid & 63;
        const float* arow = adj + (size_t)row * 4096;
        int cnt = 0;
        for (int base = 0; base < 4096; base += 256) {
            float4 v = *(const float4*)&arow[base + lane * 4];
            #pragma unroll
            for (int s = 0; s < 4; ++s) {
                float xv = ((const float*)&v)[s];
                unsigned long long m = __ballot(xv > 0.f);
                if (xv > 0.f) {
                    int pos = cnt + (int)__popcll(m & ((1ull << lane) - 1ull));
                    if (pos < MAXNBR) nbr_idx[row * MAXNBR + pos] = base + lane * 4 + s;
                }
                cnt += (int)__popcll(m);
            }
        }
        if (lane == 0) nbr_cnt[row] = cnt < MAXNBR ? cnt : MAXNBR;
    }
}

// ---------- K2: node-major coefs: fsp[n][8], fdp[n][8] ----------
__global__ __launch_bounds__(256) void attn_coef1(const unsigned short* __restrict__ h1h,
                                                  const float* __restrict__ a_src,
                                                  const float* __restrict__ a_dst,
                                                  float* __restrict__ fsp,
                                                  float* __restrict__ fdp) {
    int n = blockIdx.x, t = threadIdx.x;
    ushort4 v = *(const ushort4*)&h1h[(size_t)n * 1024 + t * 4];
    int head = t >> 5;
    int o0 = (t * 4) & 127;
    float hv0 = h2f(v.x), hv1 = h2f(v.y), hv2 = h2f(v.z), hv3 = h2f(v.w);
    float ps = hv0 * a_src[head * 128 + o0] + hv1 * a_src[head * 128 + o0 + 1]
             + hv2 * a_src[head * 128 + o0 + 2] + hv3 * a_src[head * 128 + o0 + 3];
    float pd = hv0 * a_dst[head * 128 + o0] + hv1 * a_dst[head * 128 + o0 + 1]
             + hv2 * a_dst[head * 128 + o0 + 2] + hv3 * a_dst[head * 128 + o0 + 3];
    #pragma unroll
    for (int off = 1; off < 32; off <<= 1) {
        ps += __shfl_xor(ps, off);
        pd += __shfl_xor(pd, off);
    }
    if ((t & 31) == 0) {
        fsp[n * 8 + head] = ps;
        fdp[n * 8 + head] = pd;
    }
}

// ---------- K3: aggregate5 — node-major coef softmax + pk-f16 gather ----------
__global__ __launch_bounds__(256, 8) void aggregate5(const unsigned short* __restrict__ h1h,
                                                     const int* __restrict__ nbr_idx,
                                                     const int* __restrict__ nbr_cnt,
                                                     const float* __restrict__ fsp,
                                                     const float* __restrict__ fdp,
                                                     unsigned short* __restrict__ h1act) {
    __shared__ int nbr[MAXNBR];
    __shared__ float e_s[8][MAXNBR];     // 4 KB
    __shared__ _Float16 attwS[8][MAXNBR];// 2 KB
    __shared__ half8 partS[128];         // 2 KB
    int i = blockIdx.x;
    int t = threadIdx.x;
    int cnt = nbr_cnt[i];
    if (t < MAXNBR) nbr[t] = (t < cnt) ? nbr_idx[i * MAXNBR + t] : 0;
    __syncthreads();
    // ---- e computation: thread j<128 loads fdp[nbr[j]][0..7] (one cacheline) ----
    if (t < MAXNBR) {
        if (t < cnt) {
            int nb = nbr[t];
            float4 fs0 = *(const float4*)&fsp[i * 8];
            float4 fs1 = *(const float4*)&fsp[i * 8 + 4];
            float4 d0 = *(const float4*)&fdp[nb * 8];
            float4 d1 = *(const float4*)&fdp[nb * 8 + 4];
            float e0 = fs0.x + d0.x, e1 = fs0.y + d0.y, e2 = fs0.z + d0.z, e3 = fs0.w + d0.w;
            float e4 = fs1.x + d1.x, e5 = fs1.y + d1.y, e6 = fs1.z + d1.z, e7 = fs1.w + d1.w;
            e_s[0][t] = e0 > 0.f ? e0 : ALPHA * e0;
            e_s[1][t] = e1 > 0.f ? e1 : ALPHA * e1;
            e_s[2][t] = e2 > 0.f ? e2 : ALPHA * e2;
            e_s[3][t] = e3 > 0.f ? e3 : ALPHA * e3;
            e_s[4][t] = e4 > 0.f ? e4 : ALPHA * e4;
            e_s[5][t] = e5 > 0.f ? e5 : ALPHA * e5;
            e_s[6][t] = e6 > 0.f ? e6 : ALPHA * e6;
            e_s[7][t] = e7 > 0.f ? e7 : ALPHA * e7;
        } else {
            #pragma unroll
            for (int h = 0; h < 8; ++h) e_s[h][t] = -INFINITY;
        }
    }
    __syncthreads();
    // ---- per-head softmax reduce: head t>>5, lanes 32, slots (t&31)+32p ----
    {
        int h = t >> 5, sl = t & 31;
        float e[4];
        #pragma unroll
        for (int p = 0; p < 4; ++p) e[p] = e_s[h][sl + p * 32];
        float m = fmaxf(fmaxf(e[0], e[1]), fmaxf(e[2], e[3]));
        #pragma unroll
        for (int off = 1; off < 32; off <<= 1) m = fmaxf(m, __shfl_xor(m, off));
        float wq[4], s = 0.f;
        #pragma unroll
        for (int p = 0; p < 4; ++p) {
            wq[p] = (e[p] == -INFINITY) ? 0.f : __expf(e[p] - m);
            s += wq[p];
        }
        #pragma unroll
        for (int off = 1; off < 32; off <<= 1) s += __shfl_xor(s, off);
        float inv = 1.f / s;
        #pragma unroll
        for (int p = 0; p < 4; ++p)
            attwS[h][sl + p * 32] = (_Float16)(wq[p] * inv);
    }
    __syncthreads();
    // ---- gather: parity par = t>>7 over neighbors; feats (t&127)*8 ----
    int tf = t & 127;
    int par = t >> 7;
    int head = tf >> 4;
    const unsigned short* src = h1h + tf * 8;
    h2v acc2[4] = {};
    int cntPad = (cnt + 3) & ~3;
    for (int j = par; j < cntPad; j += 4) {
        int nb1 = nbr[j], nb2 = nbr[j + 2];
        _Float16 w1 = attwS[head][j], w2 = attwS[head][j + 2];
        half8 v1 = *(const half8*)&src[(size_t)nb1 << 10];
        half8 v2 = *(const half8*)&src[(size_t)nb2 << 10];
        h2v w1v = (h2v){w1, w1}, w2v = (h2v){w2, w2};
        const h2v* p1 = (const h2v*)&v1;
        const h2v* p2 = (const h2v*)&v2;
        #pragma unroll
        for (int q = 0; q < 4; ++q)
            acc2[q] += w1v * p1[q] + w2v * p2[q];
    }
    if (par == 1) {
        half8 st;
        #pragma unroll
        for (int q = 0; q < 4; ++q) { st[q * 2] = acc2[q][0]; st[q * 2 + 1] = acc2[q][1]; }
        partS[tf] = st;
    }
    __syncthreads();
    if (par == 0) {
        half8 p = partS[tf];
        short8 o;
        #pragma unroll
        for (int q = 0; q < 4; ++q) {
            float a0 = (float)acc2[q][0] + (float)p[q * 2];
            float a1 = (float)acc2[q][1] + (float)p[q * 2 + 1];
            a0 = a0 > 0.f ? a0 : (__expf(a0) - 1.f);
            a1 = a1 > 0.f ? a1 : (__expf(a1) - 1.f);
            o[q * 2] = f2h(a0);
            o[q * 2 + 1] = f2h(a1);
        }
        *(short8*)&h1act[(size_t)i * 1024 + tf * 8] = o;
    }
}

// ---------- K4: layer-2 MFMA GEMM [4096x1024]@[1024x16] + packed f2 coefs ----------
__global__ __launch_bounds__(256) void layer2_mfma(const unsigned short* __restrict__ h1act,
                                                   const float* __restrict__ W2,
                                                   const float* __restrict__ a_src2,
                                                   const float* __restrict__ a_dst2,
                                                   float* __restrict__ h2,
                                                   float2* __restrict__ fsd2) {
    __shared__ unsigned short Asm2[64 * 64];       // 8 KB
    __shared__ unsigned short W2t[16 * 1032];      // 33 KB: [col][k], padded
    int t = threadIdx.x, lane = t & 63, w = t >> 6;
    int rowBase = blockIdx.x * 64;
    for (int idx = t; idx < 16384; idx += 256) {
        int k = idx >> 4, o = idx & 15;
        W2t[o * 1032 + k] = f2h(W2[idx]);
    }
    f32x4 acc = {};
    __syncthreads();
    for (int k0 = 0; k0 < 1024; k0 += 64) {
        #pragma unroll
        for (int r = 0; r < 2; ++r) {
            int rA = r * 32 + w * 8;
            __builtin_amdgcn_global_load_lds(
                (const __attribute__((address_space(1))) void*)&h1act[(size_t)(rowBase + rA + (lane >> 3)) * 1024 + k0 + (lane & 7) * 8],
                (__attribute__((address_space(3))) void*)&Asm2[rA * 64],
                16, 0, 0);
        }
        __syncthreads();
        #pragma unroll
        for (int kk = 0; kk < 64; kk += 32) {
            half8 af = *(const half8*)&Asm2[(w * 16 + (lane & 15)) * 64 + kk + (lane >> 4) * 8];
            half8 bf = *(const half8*)&W2t[(lane & 15) * 1032 + k0 + kk + (lane >> 4) * 8];
            acc = __builtin_amdgcn_mfma_f32_16x16x32_f16(af, bf, acc, 0, 0, 0);
        }
        __syncthreads();
    }
    int col = lane & 15;
    int g = lane >> 4;
    #pragma unroll
    for (int r = 0; r < 4; ++r) {
        int row = rowBase + w * 16 + g * 4 + r;
        float v = acc[r];
        h2[row * 16 + col] = v;
        float ps = v * a_src2[col];
        float pd = v * a_dst2[col];
        #pragma unroll
        for (int off = 1; off < 16; off <<= 1) {
            ps += __shfl_xor(ps, off);
            pd += __shfl_xor(pd, off);
        }
        if (col == 0) fsd2[row] = make_float2(ps, pd);
    }
}

// ---------- K5: layer-2 aggregation + elu + log_softmax ----------
__global__ __launch_bounds__(64) void final_layer(const float* __restrict__ h2,
                                                  const int* __restrict__ nbr_idx,
                                                  const int* __restrict__ nbr_cnt,
                                                  const float2* __restrict__ fsd2,
                                                  float* __restrict__ out) {
    __shared__ float attn[MAXNBR];
    __shared__ int nbr[MAXNBR];
    int i = blockIdx.x;
    int l = threadIdx.x;
    int cnt = nbr_cnt[i];
    float fsi = fsd2[i].x;
    for (int j = l; j < MAXNBR; j += 64) {
        float e = -INFINITY;
        if (j < cnt) {
            int jj = nbr_idx[i * MAXNBR + j];
            nbr[j] = jj;
            float xv = fsi + fsd2[jj].y;
            e = xv > 0.f ? xv : ALPHA * xv;
        }
        attn[j] = e;
    }
    __syncthreads();
    float m = fmaxf(attn[l], attn[l + 64]);
    #pragma unroll
    for (int off = 1; off < 64; off <<= 1) m = fmaxf(m, __shfl_xor(m, off));
    float s = 0.f;
    {
        float e0 = attn[l], e1 = attn[l + 64];
        if (e0 != -INFINITY) s += __expf(e0 - m);
        if (e1 != -INFINITY) s += __expf(e1 - m);
    }
    #pragma unroll
    for (int off = 1; off < 64; off <<= 1) s += __shfl_xor(s, off);
    for (int j = l; j < MAXNBR; j += 64) {
        float e = attn[j];
        attn[j] = (e == -INFINITY) ? 0.f : __expf(e - m) / s;
    }
    __syncthreads();
    if (l < 16) {
        float acc = 0.f;
        for (int j = 0; j < cnt; ++j)
            acc += attn[j] * h2[nbr[j] * 16 + l];
        float v = acc > 0.f ? acc : expm1f(acc);
        float mx = v;
        #pragma unroll
        for (int off = 1; off < 16; off <<= 1) mx = fmaxf(mx, __shfl_xor(mx, off));
        float se = __expf(v - mx);
        #pragma unroll
        for (int off = 1; off < 16; off <<= 1) se += __shfl_xor(se, off);
        out[i * 16 + l] = v - mx - logf(se);
    }
}

extern "C" void kernel_launch(void* const* d_in, const int* in_sizes, int n_in,
                              void* d_out, int out_size, void* d_ws, size_t ws_size,
                              hipStream_t stream) {
    const float* x      = (const float*)d_in[0];
    const float* adj    = (const float*)d_in[1];
    const float* W1     = (const float*)d_in[2];
    const float* a_src1 = (const float*)d_in[3];
    const float* a_dst1 = (const float*)d_in[4];
    const float* W2     = (const float*)d_in[5];
    const float* a_src2 = (const float*)d_in[6];
    const float* a_dst2 = (const float*)d_in[7];
    float* out = (float*)d_out;

    char* ws = (char*)d_ws;
    unsigned short* xh    = (unsigned short*)ws;                      // 4 MB
    unsigned short* w1t   = (unsigned short*)(ws + (4u << 20));       // 1 MB
    unsigned short* h1h   = (unsigned short*)(ws + (6u << 20));       // 8 MB
    float* fsp   = (float*)(ws + (14u << 20));                        // 128 KB
    float* fdp   = (float*)(ws + (14u << 20) + (128u << 10));         // 128 KB
    float* h2    = (float*)(ws + (15u << 20));                        // 256 KB
    float2* fsd2 = (float2*)(ws + (15u << 20) + (256u << 10));        // 32 KB
    int* nbr_idx = (int*)(ws + (16u << 20));                          // 2 MB
    int* nbr_cnt = (int*)(ws + (18u << 20));                          // 16 KB
    unsigned short* h1act = (unsigned short*)(ws + (26u << 20));      // 8 MB

    cvt<<<3072, 256, 0, stream>>>(x, xh, W1, w1t);
    gemm_scan<<<1536, 256, 0, stream>>>(xh, w1t, h1h, adj, nbr_idx, nbr_cnt);
    attn_coef1<<<4096, 256, 0, stream>>>(h1h, a_src1, a_dst1, fsp, fdp);
    aggregate5<<<4096, 256, 0, stream>>>(h1h, nbr_idx, nbr_cnt, fsp, fdp, h1act);
    layer2_mfma<<<64, 256, 0, stream>>>(h1act, W2, a_src2, a_dst2, h2, fsd2);
    final_layer<<<4096, 64, 0, stream>>>(h2, nbr_idx, nbr_cnt, fsd2, out);
}